// Round 14
// baseline (153.679 us; speedup 1.0000x reference)
//
#include <hip/hip_runtime.h>

#define BB 2048
#define UU 4096
#define TC 64
#define ROWS 16
#define NSCAN (BB / ROWS)        // 128 scan blocks, 16 rows each

typedef __attribute__((address_space(3))) void lds_void;
typedef __attribute__((address_space(1))) const void gbl_void;

__device__ __forceinline__ void gl_lds16(const float* g, float* l) {
    // async global->LDS DMA: dest = uniform base + lane*16, source per-lane
    __builtin_amdgcn_global_load_lds((gbl_void*)g, (lds_void*)l, 16, 0, 0);
}

#if __has_builtin(__builtin_amdgcn_fractf)
#define FRACTF(x) __builtin_amdgcn_fractf(x)
#else
#define FRACTF(x) ((x) - floorf(x))
#endif

// stage one 16x64 tile into swizzled LDS: f4-slot = row*16 + (g ^ (row&7)),
// achieved by pre-swizzling the GLOBAL source (gl_lds dest is linear).
__device__ __forceinline__ void stage_tile(const float* __restrict__ src,
                                           float* dstbase, int brow, int c0, int l) {
    #pragma unroll
    for (int it = 0; it < 4; ++it) {
        int row = (it << 2) + (l >> 4);
        int gsw = (l & 15) ^ (row & 7);
        const float* g = src + (size_t)(brow + row) * UU + (size_t)(c0 + (gsw << 2));
        gl_lds16(g, dstbase + it * 256);
    }
}

__global__ __launch_bounds__(256, 1) void fused_kernel(
    const float* __restrict__ dur,
    const float* __restrict__ speech,
    const float* __restrict__ residual_prev,
    const float* __restrict__ cached_prev,
    const int* __restrict__ unit_len,
    const int* __restrict__ sealed_len,
    const int* __restrict__ committed_prev,
    float* __restrict__ out)
{
    float* mat   = out;
    float* proj  = out + (size_t)BB * UU;
    float* resid = out + 2 * (size_t)BB * UU;
    float* cach  = resid + BB;
    float* comm  = cach + (size_t)BB * UU;

    const int tid = (int)threadIdx.x;

    if (blockIdx.x >= NSCAN) {
        // ---------------- elementwise path: one row per block ----------------
        int r = (int)blockIdx.x - NSCAN;
        int L = min(unit_len[r], sealed_len[r]); L = max(0, min(L, UU));
        int P = committed_prev[r];               P = max(0, min(P, UU));
        int gs = P >> 2, ge = (L + 3) >> 2;
        bool own = P < L;
        size_t base = (size_t)r * UU;
        #pragma unroll
        for (int k2 = 0; k2 < 4; ++k2) {
            int g = (k2 << 8) + tid;                 // group index, coalesced
            if (own && g >= gs && g < ge) continue;  // scan path owns these
            int u0 = g << 2;
            float4 pv = make_float4(0.f, 0.f, 0.f, 0.f);
            if (u0 < P) pv = *reinterpret_cast<const float4*>(cached_prev + base + u0);
            float4 p4, m4;
            p4.x = (u0 + 0 < P) ? pv.x : 0.f;
            p4.y = (u0 + 1 < P) ? pv.y : 0.f;
            p4.z = (u0 + 2 < P) ? pv.z : 0.f;
            p4.w = (u0 + 3 < P) ? pv.w : 0.f;
            m4.x = (u0 + 0 < L) ? p4.x : 0.f;
            m4.y = (u0 + 1 < L) ? p4.y : 0.f;
            m4.z = (u0 + 2 < L) ? p4.z : 0.f;
            m4.w = (u0 + 3 < L) ? p4.w : 0.f;
            *reinterpret_cast<float4*>(mat  + base + u0) = m4;
            *reinterpret_cast<float4*>(proj + base + u0) = p4;
            *reinterpret_cast<float4*>(cach + base + u0) = m4;
        }
        return;
    }

    // -------- scan path: 4 waves, async SPSC pipeline (no barriers) --------
    __shared__ __align__(16) float lin[3][2][ROWS * TC];  // 24 KB staging ring
    __shared__ __align__(16) float lout[2][ROWS * TC];    // 8 KB result ring
    __shared__ __align__(16) float lcb[ROWS][4];
    __shared__ int lP[ROWS], lL[ROWS];
    __shared__ int uni2[2];
    __shared__ volatile int flg[4];   // 0: dur prepped, 1: speech prepped,
                                      // 2: chain done, 3: lout consumed

    const int w = tid >> 6;
    const int l = tid & 63;
    const int brow = (int)blockIdx.x * ROWS;

    float creg = 0.f;
    int Lr_ = 0;

    if (w == 0) {
        const bool valid = (l < ROWS);
        int Pl = 0;
        if (valid) {
            int b = brow + l;
            int Lr = min(unit_len[b], sealed_len[b]); Lr = max(0, min(Lr, UU));
            int Pr = committed_prev[b];               Pr = max(0, min(Pr, UU));
            creg = residual_prev[b];
            lP[l] = Pr; lL[l] = Lr;
            Pl = Pr; Lr_ = Lr;
            float4 cbv = make_float4(0.f, 0.f, 0.f, 0.f);
            if (Pr < Lr && (Pr & 3))
                cbv = *reinterpret_cast<const float4*>(
                    cached_prev + (size_t)b * UU + (size_t)(Pr & ~3));
            *reinterpret_cast<float4*>(&lcb[l][0]) = cbv;
        }
        int a = (valid && Pl < Lr_) ? (Pl >> 6) : 0x7fffffff;
        int h = (valid && Pl < Lr_) ? ((Lr_ + 63) >> 6) : 0;
        #pragma unroll
        for (int d2 = 1; d2 < 64; d2 <<= 1) {
            a = min(a, __shfl_xor(a, d2));
            h = max(h, __shfl_xor(h, d2));
        }
        if (l == 0) {
            uni2[0] = a; uni2[1] = h;
            flg[0] = a - 1; flg[1] = a - 1; flg[2] = a - 1; flg[3] = a - 1;
        }
    }
    __syncthreads();
    const int alo = uni2[0], ahi = uni2[1];

    if (w == 0) {
        // ------- chain wave: 7-VALU core, half-tile register ping-pong -------
        __builtin_amdgcn_s_setprio(1);
        float4 Dc[8], Mc[8], Dn[8], Mn[8];
        float c = creg;

#define PF_HALF(Dd, Mm, ss, BG) do {                                         \
        const float* Ld_ = &lin[ss][0][0];                                    \
        const float* Lm_ = &lin[ss][1][0];                                    \
        _Pragma("unroll")                                                     \
        for (int i = 0; i < 8; ++i) {                                         \
            const int slot_ = (l << 4) + (((BG) + i) ^ (l & 7));              \
            Dd[i] = *reinterpret_cast<const float4*>(Ld_ + (slot_ << 2));     \
            Mm[i] = *reinterpret_cast<const float4*>(Lm_ + (slot_ << 2));     \
        }                                                                     \
    } while (0)

#define CP_HALF(Dd, Mm, BG, tt) do {                                          \
        float* LO_ = &lout[(tt) & 1][0];                                      \
        _Pragma("unroll")                                                     \
        for (int i = 0; i < 8; ++i) {                                         \
            float fv_[4];                                                     \
            _Pragma("unroll")                                                 \
            for (int j = 0; j < 4; ++j) {                                     \
                float d_ = ((const float*)&Dd[i])[j];                         \
                float m_ = ((const float*)&Mm[i])[j];                         \
                float s_  = d_ + c;                 /* dep 1 */               \
                float t1_ = fmaxf(s_, 0.f);                                   \
                float fr_ = FRACTF(s_);             /* dep 2 */               \
                float alt_ = t1_ - m_;                                        \
                c = (s_ >= m_) ? fr_ : alt_;        /* dep 3 */               \
                fv_[j] = t1_ - c;                                             \
            }                                                                 \
            const int slot_ = (l << 4) + (((BG) + i) ^ (l & 7));              \
            *reinterpret_cast<float4*>(LO_ + (slot_ << 2)) =                  \
                make_float4(fv_[0], fv_[1], fv_[2], fv_[3]);                  \
        }                                                                     \
    } while (0)

        if (alo < ahi) {
            while (flg[0] < alo || flg[1] < alo) { }
            asm volatile("" ::: "memory");
            if (l < ROWS) PF_HALF(Dc, Mc, alo % 3, 0);
            asm volatile("s_waitcnt lgkmcnt(0)" ::: "memory");

            for (int t = alo; t < ahi; ++t) {
                const int tn = (t + 1 < ahi) ? t + 1 : t;
                for (;;) {
                    int f0 = flg[0]; int f1 = flg[1]; int f3 = flg[3];
                    if (f0 >= tn && f1 >= tn && f3 >= t - 2) break;
                }
                asm volatile("" ::: "memory");
                const int s3 = t % 3;
                const int s3n = (t + 1) % 3;
                if (l < ROWS) {
                    PF_HALF(Dn, Mn, s3, 8);                  // half1 of t
                    __builtin_amdgcn_sched_barrier(0);
                    CP_HALF(Dc, Mc, 0, t);                   // compute half0
                    asm volatile("s_waitcnt lgkmcnt(0)" ::: "memory");
                    if (t + 1 < ahi) PF_HALF(Dc, Mc, s3n, 0); // half0 of t+1
                    __builtin_amdgcn_sched_barrier(0);
                    CP_HALF(Dn, Mn, 8, t);                   // compute half1
                }
                asm volatile("s_waitcnt lgkmcnt(0)" ::: "memory");
                if (l == 0) flg[2] = t;
            }
        }
        __builtin_amdgcn_s_setprio(0);
        if (l < ROWS) {
            int b = brow + l;
            resid[b] = c;
            comm[b]  = (float)Lr_;
        }
    } else if (w == 3) {
        // ---------------- store wave ----------------
        const int cg = l & 15;
        int Pr4[4], Lr4[4];
        #pragma unroll
        for (int it = 0; it < 4; ++it) {
            int row = (it << 2) + (l >> 4);
            Pr4[it] = lP[row];
            Lr4[it] = lL[row];
        }
        for (int t = alo; t < ahi; ++t) {
            while (flg[2] < t) { }
            asm volatile("" ::: "memory");
            const float* LO = &lout[t & 1][0];
            float4 vv[4];
            #pragma unroll
            for (int it = 0; it < 4; ++it) {
                const int row = (it << 2) + (l >> 4);
                const int slot = (row << 4) + (cg ^ (row & 7));
                vv[it] = *reinterpret_cast<const float4*>(LO + (slot << 2));
            }
            asm volatile("s_waitcnt lgkmcnt(0)" ::: "memory");  // reads retired
            if (l == 0) flg[3] = t;                             // free lout early
            #pragma unroll
            for (int it = 0; it < 4; ++it) {
                const int row = (it << 2) + (l >> 4);
                float4 v = vv[it];
                const int gg = (t << 4) + cg;
                const int Pr = Pr4[it], Lr = Lr4[it];
                const int u0 = gg << 2;
                bool instore = (Pr < Lr) && (gg >= (Pr >> 2)) && (gg < ((Lr + 3) >> 2));
                if (instore) {
                    if (u0 < Pr) {                     // partial P-boundary group
                        float4 cbv = *reinterpret_cast<const float4*>(&lcb[row][0]);
                        v.x = (u0 + 0 >= Pr) ? v.x : cbv.x;
                        v.y = (u0 + 1 >= Pr) ? v.y : cbv.y;
                        v.z = (u0 + 2 >= Pr) ? v.z : cbv.z;
                        v.w = (u0 + 3 >= Pr) ? v.w : cbv.w;
                    }
                    if (u0 + 4 > Lr) {                 // partial L-tail group
                        v.x = (u0 + 0 < Lr) ? v.x : 0.f;
                        v.y = (u0 + 1 < Lr) ? v.y : 0.f;
                        v.z = (u0 + 2 < Lr) ? v.z : 0.f;
                        v.w = (u0 + 3 < Lr) ? v.w : 0.f;
                    }
                    size_t o = (size_t)(brow + row) * UU + (size_t)u0;
                    *reinterpret_cast<float4*>(mat  + o) = v;
                    *reinterpret_cast<float4*>(proj + o) = v;
                    *reinterpret_cast<float4*>(cach + o) = v;
                }
            }
        }
    } else {
        // ------- stage+prep waves (w==1: dur, w==2: speech->mask) -------
        const float* src = (w == 1) ? dur : speech;
        volatile int* myf = &flg[w - 1];
        const int arr = w - 1;
        const int r_ = l >> 2;
        const int Pr_ = lP[r_];
        const int Lr2_ = lL[r_];
        const unsigned span_ = (Lr2_ > Pr_) ? (unsigned)(Lr2_ - Pr_) : 0u;

#define PREP_TILE(qq) do {                                                    \
        const int c0_ = (qq) << 6;                                            \
        float* Lp_ = &lin[(qq) % 3][arr][0];                                  \
        const int kb_ = ((l & 3) << 4) - (Pr_ - c0_);                         \
        _Pragma("unroll")                                                     \
        for (int gi = 0; gi < 4; ++gi) {                                      \
            const int g_ = ((l & 3) << 2) + gi;                               \
            const int slot_ = (r_ << 4) + (g_ ^ (r_ & 7));                    \
            float4 v_ = *reinterpret_cast<const float4*>(Lp_ + (slot_ << 2)); \
            float o_[4];                                                      \
            float in_[4] = {v_.x, v_.y, v_.z, v_.w};                          \
            _Pragma("unroll")                                                 \
            for (int j = 0; j < 4; ++j) {                                     \
                bool va_ = (unsigned)(kb_ + (gi << 2) + j) < span_;           \
                float x_ = in_[j];                                            \
                if (arr == 1) x_ = (x_ > 0.5f) ? 1.0f : 0.0f;                 \
                o_[j] = va_ ? x_ : 1.0f;                                      \
            }                                                                 \
            *reinterpret_cast<float4*>(Lp_ + (slot_ << 2)) =                  \
                make_float4(o_[0], o_[1], o_[2], o_[3]);                      \
        }                                                                     \
    } while (0)

        for (int q = alo; q < ahi; ++q) {
            while (flg[2] < q - 3) { }               // lin slot q%3 free
            asm volatile("" ::: "memory");
            stage_tile(src, &lin[q % 3][arr][0], brow, q << 6, l);
            // in-order vm retirement: <=4 outstanding => tile q-1 landed
            asm volatile("s_waitcnt vmcnt(4)" ::: "memory");
            if (q > alo) {
                PREP_TILE(q - 1);
                asm volatile("s_waitcnt lgkmcnt(0)" ::: "memory");
            }
            if (l == 0) *myf = q - 1;
        }
        if (alo < ahi) {
            asm volatile("s_waitcnt vmcnt(0)" ::: "memory");
            PREP_TILE(ahi - 1);
            asm volatile("s_waitcnt lgkmcnt(0)" ::: "memory");
            if (l == 0) *myf = ahi - 1;
        }
    }
}

extern "C" void kernel_launch(void* const* d_in, const int* in_sizes, int n_in,
                              void* d_out, int out_size, void* d_ws, size_t ws_size,
                              hipStream_t stream) {
    const float* dur            = (const float*)d_in[0];
    const float* speech         = (const float*)d_in[1];
    const float* residual_prev  = (const float*)d_in[2];
    const float* cached_prev    = (const float*)d_in[3];
    const int*   unit_len       = (const int*)d_in[4];
    const int*   sealed_len     = (const int*)d_in[5];
    const int*   committed_prev = (const int*)d_in[6];

    fused_kernel<<<NSCAN + BB, 256, 0, stream>>>(dur, speech, residual_prev, cached_prev,
                                                 unit_len, sealed_len, committed_prev,
                                                 (float*)d_out);
}

// Round 15
// 60.357 us; speedup vs baseline: 2.5462x; 2.5462x over previous
//
#include <hip/hip_runtime.h>

#define BB 2048
#define UU 4096
#define CH 512
#define NCH (UU / CH)   // 8 chunks per row

#if __has_builtin(__builtin_amdgcn_fractf)
#define FRACTF(x) __builtin_amdgcn_fractf(x)
#else
#define FRACTF(x) ((x) - floorf(x))
#endif

#if __has_builtin(__builtin_amdgcn_fmed3f)
#define FMED3(a,b,c) __builtin_amdgcn_fmed3f((a),(b),(c))
#else
__device__ __forceinline__ float FMED3(float a, float b, float c) {
    return fmaxf(fminf(a, b), fminf(fmaxf(a, b), c));
}
#endif

// One row per 64-thread block. Lane l owns columns [base + 8l, base + 8l + 8).
// Serial carry crosses lanes via readlane broadcast; step is
// c' = med3(fract(s), s + A, A), s = d' + c, A = -m'  (bit-exact vs reference;
// inactive elements substituted d'=1, A=-1 make the step an exact identity on
// c in [-1,1)). frames reconstructed wave-parallel post-loop from saved c-in.
__global__ __launch_bounds__(64) void row_kernel(
    const float* __restrict__ dur,
    const float* __restrict__ speech,
    const float* __restrict__ residual_prev,
    const float* __restrict__ cached_prev,
    const int* __restrict__ unit_len,
    const int* __restrict__ sealed_len,
    const int* __restrict__ committed_prev,
    float* __restrict__ out)
{
    float* mat   = out;
    float* proj  = out + (size_t)BB * UU;
    float* resid = out + 2 * (size_t)BB * UU;
    float* cach  = resid + BB;
    float* comm  = cach + (size_t)BB * UU;

    const int r = (int)blockIdx.x;
    const int l = (int)threadIdx.x;
    int L = min(unit_len[r], sealed_len[r]); L = max(0, min(L, UU));
    int P = committed_prev[r];               P = max(0, min(P, UU));
    const unsigned span = (L > P) ? (unsigned)(L - P) : 0u;
    float carry = residual_prev[r];
    const size_t ro = (size_t)r * UU;
    const int off = l << 3;

    float4 z4 = make_float4(0.f, 0.f, 0.f, 0.f);
    float4 dA0=z4,dA1=z4,sA0=z4,sA1=z4,cA0=z4,cA1=z4;
    float4 dB0=z4,dB1=z4,sB0=z4,sB1=z4,cB0=z4,cB1=z4;

    // prologue: load chunk 0 (uniform-per-row conditionals)
    {
        const bool needDS = (0 < L) && (CH > P);
        const bool needC  = (P > 0);
        if (needDS) {
            dA0 = *(const float4*)(dur + ro + off);
            dA1 = *(const float4*)(dur + ro + off + 4);
            sA0 = *(const float4*)(speech + ro + off);
            sA1 = *(const float4*)(speech + ro + off + 4);
        }
        if (needC) {
            cA0 = *(const float4*)(cached_prev + ro + off);
            cA1 = *(const float4*)(cached_prev + ro + off + 4);
        }
    }

    #pragma unroll 1
    for (int k = 0; k < NCH; ++k) {
        const int base = k * CH;
        // prefetch next chunk into B regs
        if (k + 1 < NCH) {
            const int nb = base + CH;
            const bool needDS = (nb < L) && (nb + CH > P);
            const bool needC  = (nb < P);
            if (needDS) {
                dB0 = *(const float4*)(dur + ro + nb + off);
                dB1 = *(const float4*)(dur + ro + nb + off + 4);
                sB0 = *(const float4*)(speech + ro + nb + off);
                sB1 = *(const float4*)(speech + ro + nb + off + 4);
            }
            if (needC) {
                cB0 = *(const float4*)(cached_prev + ro + nb + off);
                cB1 = *(const float4*)(cached_prev + ro + nb + off + 4);
            }
        }
        // all but the <=6 newest VM ops retired => chunk k's loads landed
        // (loads(k) are older than this iteration's <=6 prefetch loads and
        //  older than last iteration's stores; safe head/steady/tail).
        asm volatile("s_waitcnt vmcnt(6)" ::: "memory");

        // wave-parallel prep: identity substitution for inactive elements
        float dd[8] = {dA0.x,dA0.y,dA0.z,dA0.w,dA1.x,dA1.y,dA1.z,dA1.w};
        float ss[8] = {sA0.x,sA0.y,sA0.z,sA0.w,sA1.x,sA1.y,sA1.z,sA1.w};
        float cp[8] = {cA0.x,cA0.y,cA0.z,cA0.w,cA1.x,cA1.y,cA1.z,cA1.w};
        const int kb = base + off - P;
        float dp[8], Am[8];
        #pragma unroll
        for (int j = 0; j < 8; ++j) {
            bool va = (unsigned)(kb + j) < span;
            dp[j] = va ? dd[j] : 1.0f;
            Am[j] = (va && (ss[j] <= 0.5f)) ? 0.0f : -1.0f;   // A = -m'
        }

        // serial segment: only lanes intersecting [P, L)
        const int lo = (max(0, P - base)) >> 3;
        const int hi = (min(CH, max(0, L - base)) + 7) >> 3;
        float cin = 0.f;
        for (int i = lo; i < hi; ++i) {
            cin = (l == i) ? carry : cin;          // save lane i's carry-in
            float cc = carry;
            #pragma unroll
            for (int j = 0; j < 8; ++j) {
                float s = dp[j] + cc;
                cc = FMED3(FRACTF(s), s + Am[j], Am[j]);   // 3-dep-level step
            }
            carry = __int_as_float(__builtin_amdgcn_readlane(__float_as_int(cc), i));
        }

        // wave-parallel post: reconstruct frames + final values (off serial path)
        float pj[8], mt[8];
        float c2 = cin;
        #pragma unroll
        for (int j = 0; j < 8; ++j) {
            float s  = dp[j] + c2;
            float t1 = fmaxf(s, 0.f);
            float cc = FMED3(FRACTF(s), s + Am[j], Am[j]);
            float fv = t1 - cc;                    // frames
            c2 = cc;
            int u = base + off + j;
            bool va = (unsigned)(u - P) < span;
            float p_ = va ? fv : ((u < P) ? cp[j] : 0.f);
            pj[j] = p_;
            mt[j] = (u < L) ? p_ : 0.f;
        }
        {
            float* pm = mat  + ro + base + off;
            float* pp = proj + ro + base + off;
            float* pc = cach + ro + base + off;
            *(float4*)(pm)     = make_float4(mt[0], mt[1], mt[2], mt[3]);
            *(float4*)(pm + 4) = make_float4(mt[4], mt[5], mt[6], mt[7]);
            *(float4*)(pp)     = make_float4(pj[0], pj[1], pj[2], pj[3]);
            *(float4*)(pp + 4) = make_float4(pj[4], pj[5], pj[6], pj[7]);
            *(float4*)(pc)     = make_float4(mt[0], mt[1], mt[2], mt[3]);
            *(float4*)(pc + 4) = make_float4(mt[4], mt[5], mt[6], mt[7]);
        }
        // pin store issue before next iteration's prefetch (keeps vmcnt math)
        asm volatile("" ::: "memory");

        dA0=dB0; dA1=dB1; sA0=sB0; sA1=sB1; cA0=cB0; cA1=cB1;
    }

    if (l == 0) {
        resid[r] = carry;
        comm[r]  = (float)L;
    }
}

extern "C" void kernel_launch(void* const* d_in, const int* in_sizes, int n_in,
                              void* d_out, int out_size, void* d_ws, size_t ws_size,
                              hipStream_t stream) {
    const float* dur            = (const float*)d_in[0];
    const float* speech         = (const float*)d_in[1];
    const float* residual_prev  = (const float*)d_in[2];
    const float* cached_prev    = (const float*)d_in[3];
    const int*   unit_len       = (const int*)d_in[4];
    const int*   sealed_len     = (const int*)d_in[5];
    const int*   committed_prev = (const int*)d_in[6];

    row_kernel<<<BB, 64, 0, stream>>>(dur, speech, residual_prev, cached_prev,
                                      unit_len, sealed_len, committed_prev,
                                      (float*)d_out);
}